// Round 4
// baseline (124.914 us; speedup 1.0000x reference)
//
#include <hip/hip_runtime.h>

// Problem constants (fixed by the reference setup)
#define B_   16
#define C_   64
#define H_   128
#define W_   128
#define HO   126
#define WO   126
#define NK   8     // number of conv kernels
#define ROWS 42    // output rows per block (126 = 3 * 42)
#define INR  44    // input rows staged = ROWS + 2

// Block = (band, channel, batch), 512 threads = 8 waves.
// Wave w owns output kernel-plane k=w for the whole band: it writes a single
// contiguous, monotonically ascending 21 KB stream (42 rows x 504 B).
// Lane l computes wo = l and wo = 64+l via a rolling 3-row tap window held in
// registers (6 LDS reads per row). Weights live in SGPRs (readfirstlane'd
// wave index -> scalar loads), so v_fma uses SGPR*VGPR.
__global__ __launch_bounds__(512) void conv_silu_kernel(
    const float* __restrict__ x, const float* __restrict__ Wt,
    float* __restrict__ out)
{
    __shared__ float s[INR][W_];   // 44 * 128 * 4 B = 22.5 KiB

    const int band = blockIdx.x;   // 0..2
    const int c    = blockIdx.y;   // 0..63
    const int b    = blockIdx.z;   // 0..15
    const int tid  = threadIdx.x;  // 0..511
    const int ho0  = band * ROWS;

    // ---- stage input band (44 rows x 128 cols) with SiLU applied ----
    // 44*128 floats = 1408 float4; 512 threads -> 3 iters, last partial.
    // Always in-bounds vertically: ho0 max = 84, +43 = 127 = H-1.
    {
        const float4* xv =
            (const float4*)(x + ((size_t)(b * C_ + c) * H_ + ho0) * W_);
#pragma unroll
        for (int i = 0; i < 3; ++i) {
            const int f = tid + i * 512;         // float4 index
            if (f < INR * (W_ / 4)) {
                const float4 v = xv[f];
                const int row = f >> 5;          // 32 float4 per row
                const int col = (f & 31) << 2;
                float4 sv;
                sv.x = v.x * __builtin_amdgcn_rcpf(1.0f + __expf(-v.x));
                sv.y = v.y * __builtin_amdgcn_rcpf(1.0f + __expf(-v.y));
                sv.z = v.z * __builtin_amdgcn_rcpf(1.0f + __expf(-v.z));
                sv.w = v.w * __builtin_amdgcn_rcpf(1.0f + __expf(-v.w));
                *(float4*)&s[row][col] = sv;     // ds_write_b128
            }
        }
    }
    __syncthreads();

    // ---- compute: wave w handles kernel k = w ----
    const int l  = tid & 63;
    const int ws = __builtin_amdgcn_readfirstlane((int)(threadIdx.x >> 6)); // SGPR

    float w9[9];  // scalar loads (uniform address) -> SGPRs
#pragma unroll
    for (int j = 0; j < 9; ++j) w9[j] = Wt[ws * 9 + j];

    float* op = out + ((size_t)((b * C_ + c) * NK + ws) * HO + ho0) * WO;

    // Rolling tap window: t*[j][d] = silu(x)[input row r+j][wo + d]
    float tA[3][3], tB[3][3];
#pragma unroll
    for (int j = 0; j < 3; ++j) {
#pragma unroll
        for (int d = 0; d < 3; ++d) {
            tA[j][d] = s[j][l + d];                // cols 0..65, in-bounds
            tB[j][d] = s[j][(64 + l + d) & 127];   // masked lanes read junk, ok
        }
    }

#pragma unroll
    for (int r = 0; r < ROWS; ++r) {
        float accA = 0.f, accB = 0.f;
#pragma unroll
        for (int j = 0; j < 3; ++j) {
#pragma unroll
            for (int d = 0; d < 3; ++d) {
                const float ww = w9[j * 3 + d];
                accA += ww * tA[j][d];
                accB += ww * tB[j][d];
            }
        }
        op[r * WO + l] = accA;                     // wo = 0..63
        if (l < 62) op[r * WO + 64 + l] = accB;    // wo = 64..125

        if (r < ROWS - 1) {
            // rotate window and pull in input row r+3 (max 43 = INR-1)
#pragma unroll
            for (int j = 0; j < 2; ++j) {
#pragma unroll
                for (int d = 0; d < 3; ++d) {
                    tA[j][d] = tA[j + 1][d];
                    tB[j][d] = tB[j + 1][d];
                }
            }
#pragma unroll
            for (int d = 0; d < 3; ++d) {
                tA[2][d] = s[r + 3][l + d];
                tB[2][d] = s[r + 3][(64 + l + d) & 127];
            }
        }
    }
}

extern "C" void kernel_launch(void* const* d_in, const int* in_sizes, int n_in,
                              void* d_out, int out_size, void* d_ws, size_t ws_size,
                              hipStream_t stream) {
    const float* x  = (const float*)d_in[0];   // [16,64,128,128] f32
    const float* Wt = (const float*)d_in[1];   // [8,9] f32
    float* out = (float*)d_out;                // [16,512,126,126] f32

    dim3 grid(3, C_, B_);   // (bands, channels, batch)
    conv_silu_kernel<<<grid, 512, 0, stream>>>(x, Wt, out);
}